// Round 7
// baseline (260.941 us; speedup 1.0000x reference)
//
#include <hip/hip_runtime.h>
#include <math.h>

// LSQ quantizer with Hadamard rotation via FWHT:
//   out_row = FWHT( h0 .* s .* rint(clamp(FWHT(x_row) .* h0 / s, -Qn, Qp)) )
// with h0 = hadamard[0,:] = signs/sqrt(D).
//
// Round-8: ZERO-LDS kernel. All 11 butterfly stages run in layout A:
//   j0,j1   : float4 component add/sub            (1 VALU op/float)
//   j8..j10 : register-pair add/sub               (1 VALU op/float)
//   j2,j3   : DPP quad_perm xor1/xor2 + fma(+-1)  (2 VALU ops/float)
//   j4,j5   : ds_swizzle xor4/xor8 + fma(+-1)     (1 DS + 1 VALU/float)
//   j6,j7   : permlane16/32_swap pairing trick    (2 VALU ops/float)
// No LDS allocation, no barriers, no lgkmcnt(0) drains -> occupancy cap
// moves from 20 waves/CU (8KiB LDS/wave) to VGPR-bound (~24 waves/CU),
// and each wave's serial chain loses both transpose round-trips.
// DPP/swizzle/permlane semantics are verified by a wave-uniform runtime
// probe; any mismatch selects the known-correct all-__shfl_xor fallback.
//
// Layout A: j = r*256 + lane*4 + c  (comps=j[0:2], lanes=j[2:8], regs=j[8:11])

constexpr int D  = 2048;
constexpr int NR = 8;   // float4 regs per lane: 8 * 4 * 64 = 2048

typedef unsigned uint2v __attribute__((ext_vector_type(2)));
typedef float    f4v    __attribute__((ext_vector_type(4)));

__device__ __forceinline__ void bfly(float4& a, float4& b) {
    float4 ta = a, tb = b;
    a.x = ta.x + tb.x; a.y = ta.y + tb.y; a.z = ta.z + tb.z; a.w = ta.w + tb.w;
    b.x = ta.x - tb.x; b.y = ta.y - tb.y; b.z = ta.z - tb.z; b.w = ta.w - tb.w;
}

__device__ __forceinline__ void reg_stages(float4 (&v)[NR]) {   // j8,j9,j10
    #pragma unroll
    for (int m = 1; m <= 4; m <<= 1) {
        #pragma unroll
        for (int r = 0; r < NR; ++r)
            if ((r & m) == 0) bfly(v[r], v[r | m]);
    }
}

__device__ __forceinline__ void comp_stages(float4 (&v)[NR]) {  // j0,j1
    #pragma unroll
    for (int r = 0; r < NR; ++r) {
        float a, b;
        a = v[r].x; b = v[r].y; v[r].x = a + b; v[r].y = a - b;
        a = v[r].z; b = v[r].w; v[r].z = a + b; v[r].w = a - b;
        a = v[r].x; b = v[r].z; v[r].x = a + b; v[r].z = a - b;
        a = v[r].y; b = v[r].w; v[r].y = a + b; v[r].w = a - b;
    }
}

// ---- DPP quad_perm partner fetch (xor1: 0xB1, xor2: 0x4E) ----
template<int CTRL>
__device__ __forceinline__ float dpp_partner(float x) {
#if __has_builtin(__builtin_amdgcn_update_dpp)
    return __builtin_bit_cast(float, __builtin_amdgcn_update_dpp(
        0, __builtin_bit_cast(int, x), CTRL, 0xF, 0xF, true));
#else
    return 0.0f;   // probe will fail -> fallback path used
#endif
}

// ---- ds_swizzle partner fetch (xor4: 0x101F, xor8: 0x201F) ----
template<int OFF>
__device__ __forceinline__ float dsz_partner(float x) {
#if __has_builtin(__builtin_amdgcn_ds_swizzle)
    return __builtin_bit_cast(float, __builtin_amdgcn_ds_swizzle(
        __builtin_bit_cast(int, x), OFF));
#else
    return 0.0f;
#endif
}

// butterfly via partner+fma: self bit=0 -> self+t, bit=1 -> t-self.
// fmaf(+-1, self, t) is exact (add/sub).
template<int CTRL>
__device__ __forceinline__ void dpp_stage(float4 (&v)[NR], float sgn) {
    #pragma unroll
    for (int r = 0; r < NR; ++r) {
        float tx = dpp_partner<CTRL>(v[r].x);
        float ty = dpp_partner<CTRL>(v[r].y);
        float tz = dpp_partner<CTRL>(v[r].z);
        float tw = dpp_partner<CTRL>(v[r].w);
        v[r].x = fmaf(sgn, v[r].x, tx);
        v[r].y = fmaf(sgn, v[r].y, ty);
        v[r].z = fmaf(sgn, v[r].z, tz);
        v[r].w = fmaf(sgn, v[r].w, tw);
    }
}
template<int OFF>
__device__ __forceinline__ void dsz_stage(float4 (&v)[NR], float sgn) {
    #pragma unroll
    for (int r = 0; r < NR; ++r) {
        float tx = dsz_partner<OFF>(v[r].x);
        float ty = dsz_partner<OFF>(v[r].y);
        float tz = dsz_partner<OFF>(v[r].z);
        float tw = dsz_partner<OFF>(v[r].w);
        v[r].x = fmaf(sgn, v[r].x, tx);
        v[r].y = fmaf(sgn, v[r].y, ty);
        v[r].z = fmaf(sgn, v[r].z, tz);
        v[r].w = fmaf(sgn, v[r].w, tw);
    }
}

// ---- raw permlane swaps (semantics probed at runtime, once) ----
__device__ __forceinline__ void plswap32(float& x, float& y) {
#if __has_builtin(__builtin_amdgcn_permlane32_swap)
    uint2v t = __builtin_amdgcn_permlane32_swap(
        __builtin_bit_cast(unsigned, x), __builtin_bit_cast(unsigned, y),
        false, false);
    x = __builtin_bit_cast(float, t[0]);
    y = __builtin_bit_cast(float, t[1]);
#else
    asm volatile("v_permlane32_swap_b32 %0, %1" : "+v"(x), "+v"(y));
#endif
}
__device__ __forceinline__ void plswap16(float& x, float& y) {
#if __has_builtin(__builtin_amdgcn_permlane16_swap)
    uint2v t = __builtin_amdgcn_permlane16_swap(
        __builtin_bit_cast(unsigned, x), __builtin_bit_cast(unsigned, y),
        false, false);
    x = __builtin_bit_cast(float, t[0]);
    y = __builtin_bit_cast(float, t[1]);
#else
    asm volatile("v_permlane16_swap_b32 %0, %1" : "+v"(x), "+v"(y));
#endif
}

// Probe permlane swap semantics: variant 0..3 (4 = unknown).
//   0: a <- [a_lo,b_lo], b <- [a_hi,b_hi]   (per m-group pair)
//   1: a <- [a_hi,b_hi], b <- [a_lo,b_lo]
//   2: a <- [b_hi,a_hi], b <- [b_lo,a_lo]
//   3: a <- [b_lo,a_lo], b <- [b_hi,a_hi]
template<bool IS32>
__device__ __forceinline__ int probe_var(int lane) {
    const int m = IS32 ? 32 : 16;
    float a = (float)lane, b = 1000.0f + (float)lane;
    if (IS32) plswap32(a, b); else plswap16(a, b);
    const bool hi = (lane & m) != 0;
    const float ea0 = hi ? 1000.0f + (float)(lane - m) : (float)lane;
    const float eb0 = hi ? 1000.0f + (float)lane       : (float)(lane + m);
    const float ea2 = hi ? (float)lane                 : 1000.0f + (float)(lane + m);
    const float eb2 = hi ? (float)(lane - m)           : 1000.0f + (float)lane;
    if (__all(a == ea0 && b == eb0)) return 0;
    if (__all(a == eb0 && b == ea0)) return 1;
    if (__all(a == ea2 && b == eb2)) return 2;
    if (__all(a == eb2 && b == ea2)) return 3;
    return 4;
}

// Probe DPP quad_perm and ds_swizzle semantics.
__device__ __forceinline__ bool probe_fast(int lane) {
    float a = (float)lane;
    bool ok = true;
    ok = ok && __all(dpp_partner<0xB1>(a)   == (float)(lane ^ 1));
    ok = ok && __all(dpp_partner<0x4E>(a)   == (float)(lane ^ 2));
    ok = ok && __all(dsz_partner<0x101F>(a) == (float)(lane ^ 4));
    ok = ok && __all(dsz_partner<0x201F>(a) == (float)(lane ^ 8));
    return ok;
}

// Lane butterfly on group-bit m for TWO registers at once, per variant.
template<int VAR, bool IS32>
__device__ __forceinline__ void bfly_l(float& a, float& b) {
    if (IS32) plswap32(a, b); else plswap16(a, b);
    float s = a + b;
    float d = (VAR == 0 || VAR == 3) ? (a - b) : (b - a);
    if (VAR == 0)      { if (IS32) plswap32(s, d); else plswap16(s, d); a = s; b = d; }
    else if (VAR == 1) { if (IS32) plswap32(s, d); else plswap16(s, d); a = d; b = s; }
    else if (VAR == 2) { if (IS32) plswap32(d, s); else plswap16(d, s); a = d; b = s; }
    else               { if (IS32) plswap32(d, s); else plswap16(d, s); a = s; b = d; }
}

template<int VAR, bool IS32>
__device__ __forceinline__ void perm_stage(float4 (&v)[NR]) {
    #pragma unroll
    for (int r = 0; r < NR; r += 2) {
        bfly_l<VAR, IS32>(v[r].x, v[r + 1].x);
        bfly_l<VAR, IS32>(v[r].y, v[r + 1].y);
        bfly_l<VAR, IS32>(v[r].z, v[r + 1].z);
        bfly_l<VAR, IS32>(v[r].w, v[r + 1].w);
    }
}

// Known-correct fallback: xor-m butterfly via shuffle.
__device__ __forceinline__ void shfl_stage(float4 (&v)[NR], int m, int lane) {
    const bool hi = (lane & m) != 0;
    #pragma unroll
    for (int r = 0; r < NR; ++r) {
        float t;
        t = __shfl_xor(v[r].x, m); v[r].x = hi ? t - v[r].x : v[r].x + t;
        t = __shfl_xor(v[r].y, m); v[r].y = hi ? t - v[r].y : v[r].y + t;
        t = __shfl_xor(v[r].z, m); v[r].z = hi ? t - v[r].z : v[r].z + t;
        t = __shfl_xor(v[r].w, m); v[r].w = hi ? t - v[r].w : v[r].w + t;
    }
}

// Full 2048-point FWHT, entirely in layout A (no LDS).
template<int VAR>
__device__ __forceinline__ void fwht_full(float4 (&v)[NR], int lane,
                                          float s1, float s2, float s4, float s8) {
    comp_stages(v);                       // j0, j1
    reg_stages(v);                        // j8, j9, j10
    if constexpr (VAR < 4) {
        dpp_stage<0xB1>(v, s1);           // j2 (lane^1)
        dpp_stage<0x4E>(v, s2);           // j3 (lane^2)
        dsz_stage<0x101F>(v, s4);         // j4 (lane^4)
        dsz_stage<0x201F>(v, s8);         // j5 (lane^8)
        perm_stage<VAR, false>(v);        // j6 (lane^16)
        perm_stage<VAR, true >(v);        // j7 (lane^32)
    } else {
        shfl_stage(v, 1, lane);  shfl_stage(v, 2, lane);
        shfl_stage(v, 4, lane);  shfl_stage(v, 8, lane);
        shfl_stage(v, 16, lane); shfl_stage(v, 32, lane);
    }
}

__device__ __forceinline__ float quant1(float xh, float h0, float s, float inv_s,
                                        float nqn, float qp) {
    float u = xh * h0 * inv_s;
    u = fminf(fmaxf(u, nqn), qp);
    float q = rintf(u);                   // round half-to-even (jnp.round)
    return q * (s * h0);                  // *s, fold the second h0 multiply
}

template<int VAR>
__device__ __forceinline__ void fwht_body(
    const float* __restrict__ x, const float* __restrict__ hadamard,
    float* __restrict__ out, int lane, int row,
    float s, float inv_s, float nqn, float qp)
{
    const float s1 = (lane & 1) ? -1.0f : 1.0f;
    const float s2 = (lane & 2) ? -1.0f : 1.0f;
    const float s4 = (lane & 4) ? -1.0f : 1.0f;
    const float s8 = (lane & 8) ? -1.0f : 1.0f;

    // load x and h0, both in layout A (coalesced)
    float4 v[NR], h[NR];
    {
        const float4* x4 = reinterpret_cast<const float4*>(x + (size_t)row * D) + lane;
        const float4* h4 = reinterpret_cast<const float4*>(hadamard) + lane;
        #pragma unroll
        for (int r = 0; r < NR; ++r) v[r] = x4[(size_t)r * 64];
        #pragma unroll
        for (int r = 0; r < NR; ++r) h[r] = h4[(size_t)r * 64];
    }

    fwht_full<VAR>(v, lane, s1, s2, s4, s8);

    #pragma unroll
    for (int r = 0; r < NR; ++r) {
        v[r].x = quant1(v[r].x, h[r].x, s, inv_s, nqn, qp);
        v[r].y = quant1(v[r].y, h[r].y, s, inv_s, nqn, qp);
        v[r].z = quant1(v[r].z, h[r].z, s, inv_s, nqn, qp);
        v[r].w = quant1(v[r].w, h[r].w, s, inv_s, nqn, qp);
    }

    fwht_full<VAR>(v, lane, s1, s2, s4, s8);

    // store (layout A, coalesced, nontemporal)
    f4v* y4 = reinterpret_cast<f4v*>(out + (size_t)row * D) + lane;
    #pragma unroll
    for (int r = 0; r < NR; ++r)
        __builtin_nontemporal_store(__builtin_bit_cast(f4v, v[r]),
                                    &y4[(size_t)r * 64]);
}

__global__ __launch_bounds__(256, 4) void lsq_fwht_kernel(
    const float* __restrict__ x,
    const float* __restrict__ scale,
    const float* __restrict__ hadamard,
    const int*   __restrict__ qn_p,
    const int*   __restrict__ qp_p,
    const int*   __restrict__ ne_p,
    float*       __restrict__ out,
    int rows)
{
    const int lane = threadIdx.x & 63;
    const int wave = threadIdx.x >> 6;
    const int row  = blockIdx.x * 4 + wave;   // one wave per row
    if (row >= rows) return;

    // probe cross-lane primitive semantics once (wave-uniform)
    const int p32v = probe_var<true>(lane);
    const int p16v = probe_var<false>(lane);
    const int var  = (p32v == p16v && probe_fast(lane)) ? p32v : 4;

    // LSQ scale trick (forward value == scale), fp32 rounding as in reference
    const float sc    = scale[0];
    const float qp    = (float)qp_p[0];
    const float nqn   = -(float)qn_p[0];
    const float gs    = 1.0f / sqrtf((float)ne_p[0] * qp);
    const float bw    = sc * gs;
    const float s     = (sc - bw) + bw;
    const float inv_s = 1.0f / s;

    switch (var) {
    case 0:  fwht_body<0>(x, hadamard, out, lane, row, s, inv_s, nqn, qp); break;
    case 1:  fwht_body<1>(x, hadamard, out, lane, row, s, inv_s, nqn, qp); break;
    case 2:  fwht_body<2>(x, hadamard, out, lane, row, s, inv_s, nqn, qp); break;
    case 3:  fwht_body<3>(x, hadamard, out, lane, row, s, inv_s, nqn, qp); break;
    default: fwht_body<4>(x, hadamard, out, lane, row, s, inv_s, nqn, qp); break;
    }
}

extern "C" void kernel_launch(void* const* d_in, const int* in_sizes, int n_in,
                              void* d_out, int out_size, void* d_ws, size_t ws_size,
                              hipStream_t stream) {
    const float* x        = (const float*)d_in[0];
    const float* scale    = (const float*)d_in[1];
    const float* hadamard = (const float*)d_in[2];
    const int*   Qn       = (const int*)d_in[3];
    const int*   Qp       = (const int*)d_in[4];
    const int*   ne       = (const int*)d_in[5];
    float*       out      = (float*)d_out;

    const int rows = in_sizes[0] / D;          // 16384 for B=4,S=4096
    const int grid = (rows + 3) / 4;           // 4 waves (rows) per block

    lsq_fwht_kernel<<<grid, 256, 0, stream>>>(x, scale, hadamard, Qn, Qp, ne,
                                              out, rows);
}